// Round 9
// baseline (332.977 us; speedup 1.0000x reference)
//
#include <hip/hip_runtime.h>
#include <hip/hip_bf16.h>

// ChebConv K=4. out[b,v,o] = bias[o] + sum_{c<256} xs[c&3][v,(c>>2)*2+b] * Wflat[c*64+o]
// R9: XCD-affinity scatter — region r of rows handled by blocks on XCD r (via
// s_getreg XCC_ID) through an 8x64 task pool with stealing (correct under ANY
// dispatch mapping). Destination segments stay in one XCD's L2 -> write combining.
// xs bf16 x[v][b*64+f]; quad-gather pull spmm; MFMA epilogue.

#define NV 50000
#define NE 800000
#define XROW 128       // elements per x row = 2 batches * 64 features
#define NROWS 100000
#define NTILES 6250    // NROWS / 16
#define SCAN_NBLK 196
#define NREG 8
#define REGROWS 6250   // NV / NREG
#define NSLICE 64
#define CHUNK 12500    // NE / NSLICE

using u16 = unsigned short;
using u32 = unsigned int;
typedef __bf16 bf16x8 __attribute__((ext_vector_type(8)));
typedef float f32x4 __attribute__((ext_vector_type(4)));

__device__ __forceinline__ float bflo(u32 g) { return __uint_as_float(g << 16); }
__device__ __forceinline__ float bfhi(u32 g) { return __uint_as_float(g & 0xffff0000u); }
__device__ __forceinline__ u32 pack_bf2(float a, float b) {
    u16 ha = __builtin_bit_cast(u16, (__bf16)a);
    u16 hb = __builtin_bit_cast(u16, (__bf16)b);
    return (u32)ha | ((u32)hb << 16);
}
__device__ __forceinline__ float unpack_f16hi(u32 rec) {
    u16 h = (u16)(rec >> 16);
    return (float)__builtin_bit_cast(_Float16, h);
}

__global__ void zero_cnt_k(int* __restrict__ cnt, int* __restrict__ pool) {
    int i = blockIdx.x * blockDim.x + threadIdx.x;
    if (i < NV) cnt[i] = 0;
    if (i < NREG) pool[i] = 0;
}

__global__ void hist_k(const int* __restrict__ rows, int* __restrict__ cnt) {
    int i = blockIdx.x * blockDim.x + threadIdx.x;
    if (i < NE) atomicAdd(&cnt[rows[i]], 1);
}

__global__ __launch_bounds__(256) void scan1_k(const int* __restrict__ cnt, int* __restrict__ bsum) {
    __shared__ int s[256];
    int t = threadIdx.x;
    int i = blockIdx.x * 256 + t;
    s[t] = (i < NV) ? cnt[i] : 0;
    __syncthreads();
    for (int off = 128; off > 0; off >>= 1) {
        if (t < off) s[t] += s[t + off];
        __syncthreads();
    }
    if (t == 0) bsum[blockIdx.x] = s[0];
}

__global__ __launch_bounds__(256) void scan2_k(int* __restrict__ bsum) {
    __shared__ int s[256];
    int t = threadIdx.x;
    s[t] = (t < SCAN_NBLK) ? bsum[t] : 0;
    __syncthreads();
    for (int off = 1; off < 256; off <<= 1) {
        int v = (t >= off) ? s[t - off] : 0;
        __syncthreads();
        s[t] += v;
        __syncthreads();
    }
    if (t < SCAN_NBLK) bsum[t] = (t == 0) ? 0 : s[t - 1];
}

__global__ __launch_bounds__(256) void scan3_k(const int* __restrict__ cnt, const int* __restrict__ bsum,
                                               int* __restrict__ row_ptr, int* __restrict__ row_fill) {
    __shared__ int s[256];
    int t = threadIdx.x;
    int i = blockIdx.x * 256 + t;
    int myv = (i < NV) ? cnt[i] : 0;
    s[t] = myv;
    __syncthreads();
    for (int off = 1; off < 256; off <<= 1) {
        int v = (t >= off) ? s[t - off] : 0;
        __syncthreads();
        s[t] += v;
        __syncthreads();
    }
    if (i < NV) {
        int p = bsum[blockIdx.x] + s[t] - myv;
        row_ptr[i] = p;
        row_fill[i] = p;
    }
    if (blockIdx.x == 0 && t == 0) row_ptr[NV] = NE;
}

// XCD-affinity scatter. Task = (region, slice). Blocks prefer their own XCD's
// region, steal others when its pool is drained -> every task runs exactly once
// under ANY block->XCD mapping. rec = col | f16(val)<<16.
__global__ __launch_bounds__(256) void scatter_xcd_k(const int* __restrict__ rows,
                                                     const int* __restrict__ cols,
                                                     const float* __restrict__ vals,
                                                     int* __restrict__ row_fill,
                                                     u32* __restrict__ epack,
                                                     int* __restrict__ pool) {
    __shared__ int sh_xcd;
    __shared__ int sh_s;
    if (threadIdx.x == 0) {
        // s_getreg(HW_REG_XCC_ID=20, offset=0, size=32); mask to 0..7.
        u32 x = __builtin_amdgcn_s_getreg(20 | (0 << 6) | (31 << 11));
        sh_xcd = (int)(x & 7u);
    }
    __syncthreads();
    int home = sh_xcd;
    for (int rr = 0; rr < NREG; ++rr) {
        int reg = (home + rr) & 7;
        int rlo = reg * REGROWS;
        int rhi = rlo + REGROWS;
        while (true) {
            __syncthreads();
            if (threadIdx.x == 0) sh_s = atomicAdd(&pool[reg], 1);
            __syncthreads();
            int s = sh_s;
            if (s >= NSLICE) break;
            int e0 = s * CHUNK;
            int e1 = e0 + CHUNK; if (e1 > NE) e1 = NE;
            for (int e = e0 + threadIdx.x; e < e1; e += 256) {
                int r = rows[e];
                if (r >= rlo && r < rhi) {
                    int p = atomicAdd(&row_fill[r], 1);
                    u16 hv = __builtin_bit_cast(u16, (_Float16)vals[e]);
                    epack[p] = (u32)cols[e] | ((u32)hv << 16);
                }
            }
        }
    }
}

// x0[v][b*64+f] = bf16(inputs[b,v,f]); thread per uint pair
__global__ void build_x0_k(const float* __restrict__ in, u32* __restrict__ x0u) {
    int i = blockIdx.x * blockDim.x + threadIdx.x;  // uint index: v*64 + p
    if (i < NV * 64) {
        int v = i >> 6, p = i & 63;
        int b = p >> 5;
        int f = (p & 31) * 2;
        const float* src = in + (size_t)b * (NV * 64) + (size_t)v * 64 + f;
        float2 t = *(const float2*)src;
        x0u[i] = pack_bf2(t.x, t.y);
    }
}

// One wave per row, quad-gather: lane quarter q handles edge e+q, 16 lanes x 16B
// cover the 256B row. Butterfly (xor 16,32) merges quarters; lanes 0-15 store.
__global__ __launch_bounds__(256) void spmm_k(const u32* __restrict__ x,
                                              const u32* __restrict__ xprev,
                                              const int* __restrict__ row_ptr,
                                              const u32* __restrict__ epack,
                                              u32* __restrict__ xout, int mode) {
    int wave = (int)((blockIdx.x * blockDim.x + threadIdx.x) >> 6);
    u32 lane = threadIdx.x & 63;
    int row = __builtin_amdgcn_readfirstlane(wave);
    if (row >= NV) return;
    int beg = row_ptr[row];
    int end = row_ptr[row + 1];
    int q = (int)(lane >> 4);
    u32 g16 = lane & 15;

    float ax[4] = {0.f, 0.f, 0.f, 0.f};
    float ay[4] = {0.f, 0.f, 0.f, 0.f};

    int e = beg;
    for (; e + 16 <= end; e += 16) {
        u32 rec[4];
        uint4 gv[4];
        #pragma unroll
        for (int u = 0; u < 4; ++u) {
            rec[u] = epack[e + 4 * u + q];
            gv[u] = *(const uint4*)(x + ((rec[u] & 0xffffu) << 6) + (g16 << 2));
        }
        #pragma unroll
        for (int u = 0; u < 4; ++u) {
            float w = unpack_f16hi(rec[u]);
            ax[0] += w * bflo(gv[u].x); ay[0] += w * bfhi(gv[u].x);
            ax[1] += w * bflo(gv[u].y); ay[1] += w * bfhi(gv[u].y);
            ax[2] += w * bflo(gv[u].z); ay[2] += w * bfhi(gv[u].z);
            ax[3] += w * bflo(gv[u].w); ay[3] += w * bfhi(gv[u].w);
        }
    }
    for (; e < end; e += 4) {
        int rem = end - e;
        int qq = (q < rem) ? q : 0;
        u32 rec = epack[e + qq];
        float w = (q < rem) ? unpack_f16hi(rec) : 0.f;
        uint4 gv = *(const uint4*)(x + ((rec & 0xffffu) << 6) + (g16 << 2));
        ax[0] += w * bflo(gv.x); ay[0] += w * bfhi(gv.x);
        ax[1] += w * bflo(gv.y); ay[1] += w * bfhi(gv.y);
        ax[2] += w * bflo(gv.z); ay[2] += w * bfhi(gv.z);
        ax[3] += w * bflo(gv.w); ay[3] += w * bfhi(gv.w);
    }

    #pragma unroll
    for (int m = 16; m <= 32; m <<= 1) {
        #pragma unroll
        for (int j = 0; j < 4; ++j) {
            ax[j] += __shfl_xor(ax[j], m, 64);
            ay[j] += __shfl_xor(ay[j], m, 64);
        }
    }

    if (q == 0) {
        if (mode) {
            uint4 pv = *(const uint4*)(xprev + ((u32)row << 6) + (g16 << 2));
            ax[0] = 2.f * ax[0] - bflo(pv.x); ay[0] = 2.f * ay[0] - bfhi(pv.x);
            ax[1] = 2.f * ax[1] - bflo(pv.y); ay[1] = 2.f * ay[1] - bfhi(pv.y);
            ax[2] = 2.f * ax[2] - bflo(pv.z); ay[2] = 2.f * ay[2] - bfhi(pv.z);
            ax[3] = 2.f * ax[3] - bflo(pv.w); ay[3] = 2.f * ay[3] - bfhi(pv.w);
        }
        uint4 o;
        o.x = pack_bf2(ax[0], ay[0]);
        o.y = pack_bf2(ax[1], ay[1]);
        o.z = pack_bf2(ax[2], ay[2]);
        o.w = pack_bf2(ax[3], ay[3]);
        *(uint4*)(xout + ((u32)row << 6) + (g16 << 2)) = o;
    }
}

// MFMA epilogue: C[100000 x 64] = X[100000 x 256] @ W'[256 x 64] + bias.
__global__ __launch_bounds__(256) void final_k(const u16* __restrict__ x_all,
                                               const float* __restrict__ weight,
                                               const float* __restrict__ bias,
                                               float* __restrict__ out) {
    __shared__ u16 Wt[64 * 264];  // W'^T: Wt[o][c'], stride 264
    for (int i = threadIdx.x; i < 256 * 64; i += 256) {
        int c = i >> 6, o = i & 63;
        int cp = ((c & 3) << 6) | (c >> 2);  // c' = (c&3)*64 + (c>>2)
        Wt[o * 264 + cp] = __builtin_bit_cast(u16, (__bf16)weight[i]);
    }
    __syncthreads();

    int lane = threadIdx.x & 63;
    int wid = threadIdx.x >> 6;
    int tile = blockIdx.x * 4 + wid;
    if (tile >= NTILES) return;

    int m = lane & 15;
    int q8 = (lane >> 4) * 8;

    int r = tile * 16 + m;   // row = v*2+b
    int v = r >> 1, b = r & 1;
    const u16* arow = x_all + (size_t)v * XROW + b * 64;

    f32x4 acc0 = {0.f, 0.f, 0.f, 0.f};
    f32x4 acc1 = {0.f, 0.f, 0.f, 0.f};
    f32x4 acc2 = {0.f, 0.f, 0.f, 0.f};
    f32x4 acc3 = {0.f, 0.f, 0.f, 0.f};

    #pragma unroll
    for (int kb = 0; kb < 8; ++kb) {
        int cb = kb * 32 + q8;
        int arr = cb >> 6;
        int f0 = cb & 63;
        bf16x8 a = *(const bf16x8*)(arow + (size_t)arr * (NV * XROW) + f0);
        bf16x8 b0 = *(const bf16x8*)&Wt[(0 * 16 + m) * 264 + kb * 32 + q8];
        bf16x8 b1 = *(const bf16x8*)&Wt[(1 * 16 + m) * 264 + kb * 32 + q8];
        bf16x8 b2 = *(const bf16x8*)&Wt[(2 * 16 + m) * 264 + kb * 32 + q8];
        bf16x8 b3 = *(const bf16x8*)&Wt[(3 * 16 + m) * 264 + kb * 32 + q8];
        acc0 = __builtin_amdgcn_mfma_f32_16x16x32_bf16(a, b0, acc0, 0, 0, 0);
        acc1 = __builtin_amdgcn_mfma_f32_16x16x32_bf16(a, b1, acc1, 0, 0, 0);
        acc2 = __builtin_amdgcn_mfma_f32_16x16x32_bf16(a, b2, acc2, 0, 0, 0);
        acc3 = __builtin_amdgcn_mfma_f32_16x16x32_bf16(a, b3, acc3, 0, 0, 0);
    }

    float bv0 = bias[0 * 16 + m];
    float bv1 = bias[1 * 16 + m];
    float bv2 = bias[2 * 16 + m];
    float bv3 = bias[3 * 16 + m];
    int rbase = tile * 16 + (lane >> 4) * 4;
    #pragma unroll
    for (int reg = 0; reg < 4; ++reg) {
        int rr = rbase + reg;
        int vv = rr >> 1, bb = rr & 1;
        float* op = out + (size_t)bb * (NV * 64) + (size_t)vv * 64;
        op[0 * 16 + m] = acc0[reg] + bv0;
        op[1 * 16 + m] = acc1[reg] + bv1;
        op[2 * 16 + m] = acc2[reg] + bv2;
        op[3 * 16 + m] = acc3[reg] + bv3;
    }
}

extern "C" void kernel_launch(void* const* d_in, const int* in_sizes, int n_in,
                              void* d_out, int out_size, void* d_ws, size_t ws_size,
                              hipStream_t stream) {
    const float* inputs = (const float*)d_in[0];
    const float* weight = (const float*)d_in[1];
    const float* bias   = (const float*)d_in[2];
    const float* lapv   = (const float*)d_in[3];
    const int*   lrows  = (const int*)d_in[4];
    const int*   lcols  = (const int*)d_in[5];
    float* out = (float*)d_out;

    char* ws = (char*)d_ws;
    size_t o = 0;
    auto alloc = [&](size_t bytes) -> void* {
        void* p = ws + o;
        o += (bytes + 255) & ~(size_t)255;
        return p;
    };
    u16* x_all = (u16*)alloc((size_t)4 * NV * XROW * 2);  // x0..x3 contiguous, bf16
    u32* epack = (u32*)alloc((size_t)NE * 4);
    int* row_ptr = (int*)alloc((size_t)(NV + 1) * 4);
    int* row_fill = (int*)alloc((size_t)(NV + 1) * 4);
    int* cnt = (int*)alloc((size_t)NV * 4);
    int* bsum = (int*)alloc((size_t)SCAN_NBLK * 4);
    int* pool = (int*)alloc((size_t)NREG * 4);
    (void)ws_size; (void)in_sizes; (void)n_in; (void)out_size;

    u32* x0 = (u32*)(x_all + (size_t)0 * NV * XROW);
    u32* x1 = (u32*)(x_all + (size_t)1 * NV * XROW);
    u32* x2 = (u32*)(x_all + (size_t)2 * NV * XROW);
    u32* x3 = (u32*)(x_all + (size_t)3 * NV * XROW);

    zero_cnt_k<<<(NV + 255) / 256, 256, 0, stream>>>(cnt, pool);
    hist_k<<<(NE + 255) / 256, 256, 0, stream>>>(lrows, cnt);
    scan1_k<<<SCAN_NBLK, 256, 0, stream>>>(cnt, bsum);
    scan2_k<<<1, 256, 0, stream>>>(bsum);
    scan3_k<<<SCAN_NBLK, 256, 0, stream>>>(cnt, bsum, row_ptr, row_fill);
    scatter_xcd_k<<<512, 256, 0, stream>>>(lrows, lcols, lapv, row_fill, epack, pool);
    build_x0_k<<<(NV * 64 + 255) / 256, 256, 0, stream>>>(inputs, x0);

    spmm_k<<<(NV + 3) / 4, 256, 0, stream>>>(x0, nullptr, row_ptr, epack, x1, 0);
    spmm_k<<<(NV + 3) / 4, 256, 0, stream>>>(x1, x0, row_ptr, epack, x2, 1);
    spmm_k<<<(NV + 3) / 4, 256, 0, stream>>>(x2, x1, row_ptr, epack, x3, 1);

    final_k<<<(NTILES + 3) / 4, 256, 0, stream>>>(x_all, weight, bias, out);
}

// Round 11
// 288.887 us; speedup vs baseline: 1.1526x; 1.1526x over previous
//
#include <hip/hip_runtime.h>
#include <hip/hip_bf16.h>

// ChebConv K=4. out[b,v,o] = bias[o] + sum_{c<256} xs[c&3][v,(c>>2)*2+b] * Wflat[c*64+o]
// R10 (resubmit after GPU-broker timeout): CSR rows padded to multiples of 16
// (zero-weight pad recs) -> tail-free quad-gather spmm. Weight pre-permuted to
// bf16 image once; final_k does 2 tiles per wave with shared B-fragments.
// Scatter = R5 plain form (contention-free).

#define NV 50000
#define NE 800000
#define XROW 128       // elements per x row = 2 batches * 64 features
#define NROWS 100000
#define NTILES 6250    // NROWS / 16
#define SCAN_NBLK 196
#define EPMAX 1600000  // >= NE + 15*NV (padded CSR upper bound)

using u16 = unsigned short;
using u32 = unsigned int;
typedef __bf16 bf16x8 __attribute__((ext_vector_type(8)));
typedef float f32x4 __attribute__((ext_vector_type(4)));

__device__ __forceinline__ float bflo(u32 g) { return __uint_as_float(g << 16); }
__device__ __forceinline__ float bfhi(u32 g) { return __uint_as_float(g & 0xffff0000u); }
__device__ __forceinline__ u32 pack_bf2(float a, float b) {
    u16 ha = __builtin_bit_cast(u16, (__bf16)a);
    u16 hb = __builtin_bit_cast(u16, (__bf16)b);
    return (u32)ha | ((u32)hb << 16);
}
__device__ __forceinline__ float unpack_f16hi(u32 rec) {
    u16 h = (u16)(rec >> 16);
    return (float)__builtin_bit_cast(_Float16, h);
}
__device__ __forceinline__ int pad16(int n) { return (n + 15) & ~15; }

__global__ void hist_k(const int* __restrict__ rows, int* __restrict__ cnt) {
    int i = blockIdx.x * blockDim.x + threadIdx.x;
    if (i < NE) atomicAdd(&cnt[rows[i]], 1);
}

__global__ __launch_bounds__(256) void scan1_k(const int* __restrict__ cnt, int* __restrict__ bsum) {
    __shared__ int s[256];
    int t = threadIdx.x;
    int i = blockIdx.x * 256 + t;
    s[t] = (i < NV) ? pad16(cnt[i]) : 0;
    __syncthreads();
    for (int off = 128; off > 0; off >>= 1) {
        if (t < off) s[t] += s[t + off];
        __syncthreads();
    }
    if (t == 0) bsum[blockIdx.x] = s[0];
}

__global__ __launch_bounds__(256) void scan2_k(int* __restrict__ bsum) {
    __shared__ int s[256];
    int t = threadIdx.x;
    s[t] = (t < SCAN_NBLK) ? bsum[t] : 0;
    __syncthreads();
    for (int off = 1; off < 256; off <<= 1) {
        int v = (t >= off) ? s[t - off] : 0;
        __syncthreads();
        s[t] += v;
        __syncthreads();
    }
    if (t < SCAN_NBLK) bsum[t] = (t == 0) ? 0 : s[t - 1];
}

__global__ __launch_bounds__(256) void scan3_k(const int* __restrict__ cnt, const int* __restrict__ bsum,
                                               int* __restrict__ row_ptr, int* __restrict__ row_fill) {
    __shared__ int s[256];
    int t = threadIdx.x;
    int i = blockIdx.x * 256 + t;
    int myv = (i < NV) ? pad16(cnt[i]) : 0;
    s[t] = myv;
    __syncthreads();
    for (int off = 1; off < 256; off <<= 1) {
        int v = (t >= off) ? s[t - off] : 0;
        __syncthreads();
        s[t] += v;
        __syncthreads();
    }
    if (i < NV) {
        int p = bsum[blockIdx.x] + s[t] - myv;
        row_ptr[i] = p;
        row_fill[i] = p;
        if (i == NV - 1) row_ptr[NV] = p + myv;
    }
}

// One 4B store per edge: rec = col | f16(val)<<16. Pad slots stay 0 from memset.
__global__ void scatter_k(const int* __restrict__ rows, const int* __restrict__ cols,
                          const float* __restrict__ vals,
                          int* __restrict__ row_fill,
                          u32* __restrict__ epack) {
    int i = blockIdx.x * blockDim.x + threadIdx.x;
    if (i < NE) {
        int r = rows[i];
        int p = atomicAdd(&row_fill[r], 1);
        u16 hv = __builtin_bit_cast(u16, (_Float16)vals[i]);
        epack[p] = (u32)cols[i] | ((u32)hv << 16);
    }
}

// x0[v][b*64+f] = bf16(inputs[b,v,f]); thread per uint pair
__global__ void build_x0_k(const float* __restrict__ in, u32* __restrict__ x0u) {
    int i = blockIdx.x * blockDim.x + threadIdx.x;  // uint index: v*64 + p
    if (i < NV * 64) {
        int v = i >> 6, p = i & 63;
        int b = p >> 5;
        int f = (p & 31) * 2;
        const float* src = in + (size_t)b * (NV * 64) + (size_t)v * 64 + f;
        float2 t = *(const float2*)src;
        x0u[i] = pack_bf2(t.x, t.y);
    }
}

// Pre-permute weight to bf16 image: wimg[o*264 + c'] = bf16(Wflat[c*64+o]),
// c' = (c&3)*64 + (c>>2). Columns 256..263 are pad (never read).
__global__ void prep_w_k(const float* __restrict__ weight, u16* __restrict__ wimg) {
    int i = blockIdx.x * blockDim.x + threadIdx.x;
    if (i < 256 * 64) {
        int c = i >> 6, o = i & 63;
        int cp = ((c & 3) << 6) | (c >> 2);
        wimg[o * 264 + cp] = __builtin_bit_cast(u16, (__bf16)weight[i]);
    }
}

// One wave per row, quad-gather, tail-free (rows padded to 16-edge multiples).
// mode 0: L x ; 1: 2 L x - xprev
__global__ __launch_bounds__(256) void spmm_k(const u32* __restrict__ x,
                                              const u32* __restrict__ xprev,
                                              const int* __restrict__ row_ptr,
                                              const u32* __restrict__ epack,
                                              u32* __restrict__ xout, int mode) {
    int wave = (int)((blockIdx.x * blockDim.x + threadIdx.x) >> 6);
    u32 lane = threadIdx.x & 63;
    int row = __builtin_amdgcn_readfirstlane(wave);
    if (row >= NV) return;
    int beg = row_ptr[row];
    int end = row_ptr[row + 1];
    int q = (int)(lane >> 4);
    u32 g16 = lane & 15;

    float ax[4] = {0.f, 0.f, 0.f, 0.f};
    float ay[4] = {0.f, 0.f, 0.f, 0.f};

    for (int e = beg; e < end; e += 16) {
        u32 rec[4];
        uint4 gv[4];
        #pragma unroll
        for (int u = 0; u < 4; ++u) {
            rec[u] = epack[e + 4 * u + q];
            gv[u] = *(const uint4*)(x + ((rec[u] & 0xffffu) << 6) + (g16 << 2));
        }
        #pragma unroll
        for (int u = 0; u < 4; ++u) {
            float w = unpack_f16hi(rec[u]);
            ax[0] += w * bflo(gv[u].x); ay[0] += w * bfhi(gv[u].x);
            ax[1] += w * bflo(gv[u].y); ay[1] += w * bfhi(gv[u].y);
            ax[2] += w * bflo(gv[u].z); ay[2] += w * bfhi(gv[u].z);
            ax[3] += w * bflo(gv[u].w); ay[3] += w * bfhi(gv[u].w);
        }
    }

    #pragma unroll
    for (int m = 16; m <= 32; m <<= 1) {
        #pragma unroll
        for (int j = 0; j < 4; ++j) {
            ax[j] += __shfl_xor(ax[j], m, 64);
            ay[j] += __shfl_xor(ay[j], m, 64);
        }
    }

    if (q == 0) {
        if (mode) {
            uint4 pv = *(const uint4*)(xprev + ((u32)row << 6) + (g16 << 2));
            ax[0] = 2.f * ax[0] - bflo(pv.x); ay[0] = 2.f * ay[0] - bfhi(pv.x);
            ax[1] = 2.f * ax[1] - bflo(pv.y); ay[1] = 2.f * ay[1] - bfhi(pv.y);
            ax[2] = 2.f * ax[2] - bflo(pv.z); ay[2] = 2.f * ay[2] - bfhi(pv.z);
            ax[3] = 2.f * ax[3] - bflo(pv.w); ay[3] = 2.f * ay[3] - bfhi(pv.w);
        }
        uint4 o;
        o.x = pack_bf2(ax[0], ay[0]);
        o.y = pack_bf2(ax[1], ay[1]);
        o.z = pack_bf2(ax[2], ay[2]);
        o.w = pack_bf2(ax[3], ay[3]);
        *(uint4*)(xout + ((u32)row << 6) + (g16 << 2)) = o;
    }
}

// MFMA epilogue: C[100000 x 64] = X[100000 x 256] @ W'[256 x 64] + bias.
// 2 tiles per wave (shared B-frags), 8 tiles per block. W from prebuilt bf16 image.
__global__ __launch_bounds__(256) void final_k(const u16* __restrict__ x_all,
                                               const u16* __restrict__ wimg,
                                               const float* __restrict__ bias,
                                               float* __restrict__ out) {
    __shared__ u16 Wt[64 * 264];
    {
        const u32* src = (const u32*)wimg;
        u32* dst = (u32*)Wt;
        #pragma unroll 4
        for (int i = threadIdx.x; i < 64 * 264 / 2; i += 256) dst[i] = src[i];
    }
    __syncthreads();

    int lane = threadIdx.x & 63;
    int wid = threadIdx.x >> 6;
    int pair = blockIdx.x * 4 + wid;   // tiles 2*pair, 2*pair+1
    int t0 = pair * 2;
    if (t0 >= NTILES) return;

    int m = lane & 15;
    int q8 = (lane >> 4) * 8;

    int r0 = t0 * 16 + m;        // row = v*2+b, tile t0
    int r1 = r0 + 16;            // tile t0+1
    const u16* arow0 = x_all + (size_t)(r0 >> 1) * XROW + (r0 & 1) * 64;
    const u16* arow1 = x_all + (size_t)(r1 >> 1) * XROW + (r1 & 1) * 64;

    f32x4 accA[4] = {{0,0,0,0},{0,0,0,0},{0,0,0,0},{0,0,0,0}};
    f32x4 accB[4] = {{0,0,0,0},{0,0,0,0},{0,0,0,0},{0,0,0,0}};

    #pragma unroll
    for (int kb = 0; kb < 8; ++kb) {
        int cb = kb * 32 + q8;
        int arr = cb >> 6;
        int f0 = cb & 63;
        size_t aoff = (size_t)arr * (NV * XROW) + f0;
        bf16x8 a0 = *(const bf16x8*)(arow0 + aoff);
        bf16x8 a1 = *(const bf16x8*)(arow1 + aoff);
        #pragma unroll
        for (int j = 0; j < 4; ++j) {
            bf16x8 bj = *(const bf16x8*)&Wt[(j * 16 + m) * 264 + kb * 32 + q8];
            accA[j] = __builtin_amdgcn_mfma_f32_16x16x32_bf16(a0, bj, accA[j], 0, 0, 0);
            accB[j] = __builtin_amdgcn_mfma_f32_16x16x32_bf16(a1, bj, accB[j], 0, 0, 0);
        }
    }

    float bv[4];
    #pragma unroll
    for (int j = 0; j < 4; ++j) bv[j] = bias[j * 16 + m];

    #pragma unroll
    for (int half = 0; half < 2; ++half) {
        int rbase = (t0 + half) * 16 + (lane >> 4) * 4;
        f32x4* acc = half ? accB : accA;
        #pragma unroll
        for (int reg = 0; reg < 4; ++reg) {
            int rr = rbase + reg;
            float* op = out + (size_t)(rr & 1) * (NV * 64) + (size_t)(rr >> 1) * 64;
            #pragma unroll
            for (int j = 0; j < 4; ++j) op[j * 16 + m] = acc[j][reg] + bv[j];
        }
    }
}

extern "C" void kernel_launch(void* const* d_in, const int* in_sizes, int n_in,
                              void* d_out, int out_size, void* d_ws, size_t ws_size,
                              hipStream_t stream) {
    const float* inputs = (const float*)d_in[0];
    const float* weight = (const float*)d_in[1];
    const float* bias   = (const float*)d_in[2];
    const float* lapv   = (const float*)d_in[3];
    const int*   lrows  = (const int*)d_in[4];
    const int*   lcols  = (const int*)d_in[5];
    float* out = (float*)d_out;

    char* ws = (char*)d_ws;
    size_t o = 0;
    auto alloc = [&](size_t bytes) -> void* {
        void* p = ws + o;
        o += (bytes + 255) & ~(size_t)255;
        return p;
    };
    u16* x_all = (u16*)alloc((size_t)4 * NV * XROW * 2);  // x0..x3 contiguous, bf16
    u32* epack = (u32*)alloc((size_t)EPMAX * 4);
    int* row_ptr = (int*)alloc((size_t)(NV + 1) * 4);
    int* row_fill = (int*)alloc((size_t)(NV + 1) * 4);
    int* cnt = (int*)alloc((size_t)NV * 4);
    int* bsum = (int*)alloc((size_t)SCAN_NBLK * 4);
    u16* wimg = (u16*)alloc((size_t)64 * 264 * 2);
    (void)ws_size; (void)in_sizes; (void)n_in; (void)out_size;

    u32* x0 = (u32*)(x_all + (size_t)0 * NV * XROW);
    u32* x1 = (u32*)(x_all + (size_t)1 * NV * XROW);
    u32* x2 = (u32*)(x_all + (size_t)2 * NV * XROW);
    u32* x3 = (u32*)(x_all + (size_t)3 * NV * XROW);

    hipMemsetAsync(cnt, 0, (size_t)NV * 4, stream);
    hipMemsetAsync(epack, 0, (size_t)EPMAX * 4, stream);
    hist_k<<<(NE + 255) / 256, 256, 0, stream>>>(lrows, cnt);
    scan1_k<<<SCAN_NBLK, 256, 0, stream>>>(cnt, bsum);
    scan2_k<<<1, 256, 0, stream>>>(bsum);
    scan3_k<<<SCAN_NBLK, 256, 0, stream>>>(cnt, bsum, row_ptr, row_fill);
    scatter_k<<<(NE + 255) / 256, 256, 0, stream>>>(lrows, lcols, lapv, row_fill, epack);
    build_x0_k<<<(NV * 64 + 255) / 256, 256, 0, stream>>>(inputs, x0);
    prep_w_k<<<64, 256, 0, stream>>>(weight, wimg);

    spmm_k<<<(NV + 3) / 4, 256, 0, stream>>>(x0, nullptr, row_ptr, epack, x1, 0);
    spmm_k<<<(NV + 3) / 4, 256, 0, stream>>>(x1, x0, row_ptr, epack, x2, 1);
    spmm_k<<<(NV + 3) / 4, 256, 0, stream>>>(x2, x1, row_ptr, epack, x3, 1);

    final_k<<<(NTILES / 2 + 3) / 4, 256, 0, stream>>>(x_all, wimg, bias, out);
}